// Round 17
// baseline (859.158 us; speedup 1.0000x reference)
//
#include <hip/hip_runtime.h>
#include <stdint.h>

typedef unsigned short u16;
typedef unsigned int   u32;
typedef short bf16x8 __attribute__((ext_vector_type(8)));   // 8 bf16 = 4 VGPR
typedef float f32x4  __attribute__((ext_vector_type(4)));

#define NLAYER 6
#define T_TOK  134
#define MROWS  34304            // 256*134
#define QKV_E  196608           // packed qkv elems per layer (8*48*64*8)
#define O_E    65536            // packed 256x256 matrix elems
#define LSTR_E 393216           // per-layer packed stride (qkv+o+w1+w2)
#define SPV 168                 // V^T LDS row stride (u16): 16B-aligned, bank-floor reads
#define PREP_BLKS  1155
#define BIAS_BLKS  81
#define EMB_BLKS   2144         // MROWS/16

__device__ __forceinline__ float b2f(u16 u){ u32 x=((u32)u)<<16; return __builtin_bit_cast(float,x); }
__device__ __forceinline__ u16 f2b(float f){ u32 x=__builtin_bit_cast(u32,f); return (u16)((x + 0x7fffu + ((x>>16)&1u))>>16); }
__device__ __forceinline__ void mfma16(f32x4& c, bf16x8 a, bf16x8 b){
  asm("v_mfma_f32_16x16x32_bf16 %0, %1, %2, %0" : "+v"(c) : "v"(a), "v"(b));
}
__device__ __forceinline__ float gelu_f(float x){ return 0.5f*x*(1.0f+erff(x*0.70710678118654752f)); }
// async global->LDS, 16B/lane; LDS dest wave-uniform base + lane*16 (HW scatter)
__device__ __forceinline__ void gload16(const u16* g, u16* l){
  __builtin_amdgcn_global_load_lds((const __attribute__((address_space(1))) u32*)g,
                                   (__attribute__((address_space(3))) u32*)l, 16, 0, 0);
}

// ---------------- merged prologue: [0,1155) weight-pack | [1155,1236) deg+bias | [1236,3380) embed+LN1
__global__ __launch_bounds__(256) void prologue_k(
    const float* __restrict__ wq, const float* __restrict__ wk, const float* __restrict__ wv,
    const float* __restrict__ wo, const float* __restrict__ w1, const float* __restrict__ w2,
    const float* __restrict__ bq, const float* __restrict__ bk, const float* __restrict__ bv,
    u16* __restrict__ wpack, float* __restrict__ bqkv,
    const float* __restrict__ adj, const float* __restrict__ dist,
    const float* __restrict__ gamma, const float* __restrict__ noedge,
    const float* __restrict__ dscale, const float* __restrict__ v2n,
    const float* __restrict__ n2v, const float* __restrict__ vself,
    float* __restrict__ biasP,
    const float* __restrict__ x2d, const float* __restrict__ y3d,
    const float* __restrict__ je,  const float* __restrict__ inw,
    const float* __restrict__ inb, const float* __restrict__ cls,
    const float* __restrict__ lg,  const float* __restrict__ lb,
    float* __restrict__ z, u16* __restrict__ xn)
{
  const int bx = blockIdx.x;
  const int tid = threadIdx.x;
  if (bx < PREP_BLKS){
    // ---- weight packing (body verbatim from prep_k)
    const int cid = bx*256 + tid;
    if (cid < 294912) {
      const float* msrc = nullptr; int NT, c, layer = 0, isqkv = 0;
      {
        layer = cid / 49152; int r = cid - layer*49152;
        if      (r < 24576){ NT = 48; c = r;          isqkv = 1; }
        else if (r < 32768){ NT = 16; c = r - 24576;  msrc = wo + layer*65536; }
        else if (r < 40960){ NT = 16; c = r - 32768;  msrc = w1 + layer*65536; }
        else               { NT = 16; c = r - 40960;  msrc = w2 + layer*65536; }
      }
      const int lane = c & 63, ctkk = c >> 6;
      const int ct = ctkk % NT, kk = ctkk / NT;
      const int k = kk*32 + (lane>>4)*8;
      const int n = ct*16 + (lane&15);
      u16 ov[8];
      if (isqkv){
        const int sub = n >> 8, nn = n & 255;
        const float* s3 = (sub==0 ? wq : (sub==1 ? wk : wv)) + layer*65536;
#pragma unroll
        for(int j=0;j<8;j++) ov[j] = f2b(s3[(size_t)(k+j)*256 + nn]);
      } else {
#pragma unroll
        for(int j=0;j<8;j++) ov[j] = f2b(msrc[(size_t)(k+j)*256 + n]);
      }
      *(uint4*)(wpack + (size_t)cid*8) = *(uint4*)ov;
    } else {
      const int id = cid - 294912;
      if (id >= 0 && id < 576){
#pragma unroll
        for(int j=0;j<8;j++){
          const int p = id*8 + j; const int layer = p/768; const int w = p - layer*768;
          bqkv[p] = (w<256) ? bq[layer*256+w] : (w<512) ? bk[layer*256+w-256] : bv[layer*256+w-512];
        }
      }
    }
  } else if (bx < PREP_BLKS + BIAS_BLKS){
    // ---- deg (computed redundantly per block; identical serial j-loop -> bit-identical) + bias
    __shared__ float deg[134];   // [133] = 1/(max+eps)
    if (tid < 133){
      float s = 0.f;
      for (int j=0;j<133;j++) s += adj[tid*133+j];
      deg[tid] = s;
    }
    __syncthreads();
    if (tid == 0){ float m=0.f; for (int i=0;i<133;i++) m = fmaxf(m, deg[i]); deg[133] = 1.0f/(m + 1e-6f); }
    __syncthreads();
    const int idx = (bx - PREP_BLKS)*256 + tid;
    if (idx < 144*144){
      const int t = idx/144, s = idx - t*144;
      float v;
      if (s >= 134)          v = -1e30f;      // softmax mask for padded cols
      else if (t >= 134)     v = 0.f;         // garbage rows, never stored
      else if (t==0 && s==0) v = vself[0];
      else if (t==0)         v = v2n[0];
      else if (s==0)         v = n2v[0];
      else {
        const int i = t-1, j = s-1;
        float e = -gamma[0]*dist[i*133+j];
        if (!(adj[i*133+j] > 0.f)) e += noedge[0];
        e += dscale[0]*(deg[i]+deg[j])*deg[133];
        v = e;
      }
      biasP[idx] = v;
    }
  } else {
    // ---- embedding + fused LN1(layer0): 16 rows/block, wave = 4 rows (body verbatim)
    __shared__ float f[16][37];
    const int g = tid>>6, lane = tid & 63;
    const int base = (bx - PREP_BLKS - BIAS_BLKS)*16;
    for (int idx = tid; idx < 592; idx += 256){
      const int i = idx/37, j = idx - 37*i;
      const int r = base + i, b = r/134, t = r - b*134;
      if (t > 0){
        const int n = t - 1;
        float v;
        if (j < 2)      v = x2d[(size_t)(b*133+n)*2 + j];
        else if (j < 5) v = y3d[(size_t)(b*133+n)*3 + (j-2)];
        else            v = je[(size_t)n*32 + (j-5)];
        f[i][j] = v;
      }
    }
    __syncthreads();
    const int d4 = lane*4;
    const int i0 = 4*g;
    const float4 ib = *(const float4*)(inb + d4);
    float4 o0 = ib, o1 = ib, o2 = ib, o3 = ib;
#pragma unroll
    for (int i=0;i<37;i++){
      const float4 w = *(const float4*)(inw + i*256 + d4);
      const float f0 = f[i0+0][i], f1 = f[i0+1][i], f2 = f[i0+2][i], f3 = f[i0+3][i];
      o0.x += f0*w.x; o0.y += f0*w.y; o0.z += f0*w.z; o0.w += f0*w.w;
      o1.x += f1*w.x; o1.y += f1*w.y; o1.z += f1*w.z; o1.w += f1*w.w;
      o2.x += f2*w.x; o2.y += f2*w.y; o2.z += f2*w.z; o2.w += f2*w.w;
      o3.x += f3*w.x; o3.y += f3*w.y; o3.z += f3*w.z; o3.w += f3*w.w;
    }
    const float4 cv = *(const float4*)(cls + d4);
    const float4 gv = *(const float4*)(lg + d4), bv = *(const float4*)(lb + d4);
#pragma unroll
    for (int p=0;p<4;p++){
      const int r = base + i0 + p;
      const int t = r % 134;
      float4 o = (p==0) ? o0 : (p==1) ? o1 : (p==2) ? o2 : o3;
      if (t == 0) o = cv;
      *(float4*)(z + (size_t)r*256 + d4) = o;
      float s = o.x+o.y+o.z+o.w;
#pragma unroll
      for (int m=1;m<64;m<<=1) s += __shfl_xor(s, m, 64);
      const float mean = s*(1.f/256.f);
      const float dx=o.x-mean, dy=o.y-mean, dz=o.z-mean, dw=o.w-mean;
      float q = dx*dx+dy*dy+dz*dz+dw*dw;
#pragma unroll
      for (int m=1;m<64;m<<=1) q += __shfl_xor(q, m, 64);
      const float rstd = rsqrtf(q*(1.f/256.f) + 1e-5f);
      u32 p0 = (u32)f2b(dx*rstd*gv.x+bv.x) | ((u32)f2b(dy*rstd*gv.y+bv.y)<<16);
      u32 p1 = (u32)f2b(dz*rstd*gv.z+bv.z) | ((u32)f2b(dw*rstd*gv.w+bv.w)<<16);
      uint2 ov; ov.x = p0; ov.y = p1;
      *(uint2*)(xn + (size_t)r*256 + d4) = ov;
    }
  }
}

// ---------------- bf16 MFMA GEMM with global_load_lds staging (m97 pattern)
// EPI==0 (QKV) uses an XCD-chunked 1-D swizzled launch (grid 1608 = 8*201).
template<int EPI>
__global__ __launch_bounds__(256) void gemm_k(
    const u16* __restrict__ A, const u16* __restrict__ PB, const float* __restrict__ bias,
    u16* __restrict__ Obf, float* __restrict__ Of, float* __restrict__ Z, int NT)
{
  const int N = NT*16;
  __shared__ __align__(16) u16 lsA[4096];
  __shared__ __align__(16) u16 lsB[4096];
  const int tid = threadIdx.x, lane = tid & 63, wid = tid >> 6;
  int m0, n0;
  if constexpr (EPI==0){
    const int g = blockIdx.x;
    const int wg = (g & 7)*201 + (g >> 3);
    m0 = (wg/6)*128; n0 = (wg%6)*128;
  } else {
    m0 = blockIdx.x*128; n0 = blockIdx.y*128;
  }
  const int wr = wid >> 1, wc = wid & 1;
  f32x4 acc[4][4];
#pragma unroll
  for (int i=0;i<4;i++)
#pragma unroll
    for (int j=0;j<4;j++){ acc[i][j][0]=0.f; acc[i][j][1]=0.f; acc[i][j][2]=0.f; acc[i][j][3]=0.f; }

  const u16* gA0 = A + (size_t)(m0 + wid*32 + (lane&15))*256 + (lane>>4)*8;
  const u16* gA1 = gA0 + 16*256;
  u16* lA0 = lsA + wid*1024;
  u16* lA1 = lA0 + 512;
  const size_t bstr = (size_t)NT*512;
  const u16* gB0 = PB + ((size_t)((n0>>4) + wid)*64 + lane)*8;
  const u16* gB1 = gB0 + 4*512;
  u16* lB0 = lsB + wid*512;
  u16* lB1 = lB0 + 4*512;

  for (int kk=0; kk<8; ++kk){
    gload16(gA0 + kk*32, lA0);
    gload16(gA1 + kk*32, lA1);
    gload16(gB0 + (size_t)kk*bstr, lB0);
    gload16(gB1 + (size_t)kk*bstr, lB1);
    __syncthreads();
    bf16x8 af[4], bfr[4];
#pragma unroll
    for (int mi=0;mi<4;mi++) af[mi]  = *(const bf16x8*)(lsA + ((wr*4+mi)*64 + lane)*8);
#pragma unroll
    for (int ni=0;ni<4;ni++) bfr[ni] = *(const bf16x8*)(lsB + ((wc*4+ni)*64 + lane)*8);
#pragma unroll
    for (int mi=0;mi<4;mi++)
#pragma unroll
      for (int ni=0;ni<4;ni++)
        mfma16(acc[mi][ni], af[mi], bfr[ni]);
    __syncthreads();
  }
  const int r0 = (lane>>4)*4, c15 = lane & 15;
#pragma unroll
  for (int mi=0;mi<4;mi++){
#pragma unroll
    for (int ni=0;ni<4;ni++){
      const int col = n0 + wc*64 + ni*16 + c15;
      const float bv = bias[col];
#pragma unroll
      for (int r=0;r<4;r++){
        const int row = m0 + wr*64 + mi*16 + r0 + r;
        float v = acc[mi][ni][r] + bv;
        if constexpr (EPI==0){ Obf[(size_t)row*N + col] = f2b(v); }
        else if constexpr (EPI==1){ Z[(size_t)row*256 + col] += v; }
        else if constexpr (EPI==2){ Obf[(size_t)row*N + col] = f2b(gelu_f(v)); }
        else { Of[(size_t)row*N + col] = gelu_f(v); }
      }
    }
  }
}

// ---------------- fused full-row GEMM, 16 rows x 256 cols, ONE wave (64 thr).
// mode 0: Z += A*W + b ; mode 1: Z += A*W + b ; xn = LN(Z)
// Same per-row A/B-frag + kk order as the 32-row version -> bit-identical.
__global__ __launch_bounds__(64) void gemmf_k(
    const u16* __restrict__ A, const u16* __restrict__ PB, const float* __restrict__ bias,
    float* __restrict__ Z, const float* __restrict__ lg, const float* __restrict__ lb,
    u16* __restrict__ xn, int mode)
{
  __shared__ __align__(16) u16 lsA[512];    // 1 chunk  [64][8]
  __shared__ __align__(16) u16 lsB[8192];   // 16 chunks [64][8]
  const int lane = threadIdx.x & 63;
  const int m0 = blockIdx.x*16;
  f32x4 acc[16];
#pragma unroll
  for (int ni=0;ni<16;ni++){ acc[ni][0]=0.f; acc[ni][1]=0.f; acc[ni][2]=0.f; acc[ni][3]=0.f; }

  const u16* gA = A + (size_t)(m0 + (lane&15))*256 + (lane>>4)*8;
  const u16* gB0 = PB + (size_t)lane*8;

  for (int kk=0; kk<8; ++kk){
    gload16(gA + kk*32, lsA);
#pragma unroll
    for (int i=0;i<16;i++) gload16(gB0 + (size_t)kk*8192 + i*512, lsB + i*512);
    __syncthreads();
    const bf16x8 af = *(const bf16x8*)(lsA + lane*8);
#pragma unroll
    for (int ni=0;ni<16;ni++){
      const bf16x8 bfr = *(const bf16x8*)(lsB + ni*512 + lane*8);
      mfma16(acc[ni], af, bfr);
    }
    __syncthreads();
  }

  const int g4 = lane>>4, c15 = lane & 15;
  float bvs[16];
#pragma unroll
  for (int ni=0;ni<16;ni++) bvs[ni] = bias[ni*16+c15];
#pragma unroll
  for (int r=0;r<4;r++){
    const int row = m0 + g4*4 + r;
    float* zr = Z + (size_t)row*256;
    float zv[16]; float s = 0.f;
#pragma unroll
    for (int ni=0;ni<16;ni++){ zv[ni] = acc[ni][r] + bvs[ni] + zr[ni*16+c15]; s += zv[ni]; }
#pragma unroll
    for (int ni=0;ni<16;ni++) zr[ni*16+c15] = zv[ni];
    if (mode == 1){
      s += __shfl_xor(s,1,16); s += __shfl_xor(s,2,16);
      s += __shfl_xor(s,4,16); s += __shfl_xor(s,8,16);
      const float mean = s*(1.f/256.f);
      float q = 0.f;
#pragma unroll
      for (int ni=0;ni<16;ni++){ const float d = zv[ni]-mean; q += d*d; }
      q += __shfl_xor(q,1,16); q += __shfl_xor(q,2,16);
      q += __shfl_xor(q,4,16); q += __shfl_xor(q,8,16);
      const float rstd = rsqrtf(q*(1.f/256.f) + 1e-5f);
      u16* xr = xn + (size_t)row*256;
#pragma unroll
      for (int ni=0;ni<16;ni++){
        const int col = ni*16 + c15;
        xr[col] = f2b((zv[ni]-mean)*rstd*lg[col] + lb[col]);
      }
    }
  }
}

// ---------------- MFMA flash attention (round-4 math, thirds-split):
// 3 blocks per (b,h); each block = 3 waves x ONE q-tile (qt = t3*3 + w).
// Fence-1 removed (no prior Pf reads with single q-tile per wave).
// This body is the verified round-11/13 version — do not micro-edit.
__global__ __launch_bounds__(192, 6) void attn_k(
    const u16* __restrict__ qkv, const float* __restrict__ biasP, u16* __restrict__ ao)
{
  const int g0 = blockIdx.x;
  const int blk = (g0 & 7)*768 + (g0 >> 3);   // bijective XCD chunking
  const int bh = blk/3, t3 = blk - 3*bh;
  const int b = bh >> 3, h = bh & 7;
  __shared__ __align__(16) u16 Pf[3*2560];     // per-wave 5 ks * 64 lanes * 8 u16
  __shared__ __align__(16) u16 Vt[32*SPV];     // V^T [d][s], s zero-padded to 160
  const int tid = threadIdx.x, lane = tid & 63, w = tid >> 6;
  const int g = lane >> 4, c15 = lane & 15;
  const size_t base = (size_t)b*134*768 + h*32;

  if (tid < 134){
    const uint4* vr = (const uint4*)(qkv + base + (size_t)tid*768 + 512);
    uint4 w0=vr[0], w1=vr[1], w2=vr[2], w3=vr[3];
    u32 wa[8] = {w0.x,w0.y,w0.z,w0.w,w1.x,w1.y,w1.z,w1.w};
    u32 wb[8] = {w2.x,w2.y,w2.z,w2.w,w3.x,w3.y,w3.z,w3.w};
#pragma unroll
    for (int k=0;k<8;k++){
      Vt[(2*k  )*SPV + tid] = (u16)(wa[k] & 0xffffu);
      Vt[(2*k+1)*SPV + tid] = (u16)(wa[k] >> 16);
      Vt[(16+2*k  )*SPV + tid] = (u16)(wb[k] & 0xffffu);
      Vt[(16+2*k+1)*SPV + tid] = (u16)(wb[k] >> 16);
    }
  } else if (tid < 160){
#pragma unroll
    for (int d=0; d<32; d++) Vt[d*SPV + tid] = 0;
  }
  u16* Pfw = Pf + w*2560;
  const int c_r = 2*(c15>>2) + (g&1) + 8*(2*(c15&3) + (g>>1));
  if (lane >= 32){ uint4 zz; zz.x=0u; zz.y=0u; zz.z=0u; zz.w=0u;
                   *(uint4*)(Pfw + 4*512 + c_r*8) = zz; }
  __syncthreads();

  bf16x8 kf[9];
  const int kg = g*8;
#pragma unroll
  for (int st=0; st<9; st++){
    int sr = st*16 + c15; if (sr > 133) sr = 133;
    kf[st] = *(const bf16x8*)(qkv + base + (size_t)sr*768 + 256 + kg);
  }
  const float isq = 0.17677669529663687f;

  {
    const int qt = t3*3 + w;
    int qr = qt*16 + c15; if (qr > 133) qr = 133;
    const bf16x8 qf = *(const bf16x8*)(qkv + base + (size_t)qr*768 + kg);
    f32x4 s_[9];
#pragma unroll
    for (int st=0; st<9; st++){
      s_[st][0]=0.f; s_[st][1]=0.f; s_[st][2]=0.f; s_[st][3]=0.f;
      mfma16(s_[st], qf, kf[st]);
    }
    const int hi = c15 >> 3, j7 = c15 & 7;
#pragma unroll
    for (int r=0;r<4;r++){
      const float* br = biasP + (size_t)(qt*16 + g*4 + r)*144 + c15;
      float v[9];
#pragma unroll
      for (int st=0; st<9; st++) v[st] = s_[st][r]*isq + br[st*16];
      float mx = v[0];
#pragma unroll
      for (int st=1; st<9; st++) mx = fmaxf(mx, v[st]);
      mx = fmaxf(mx, __shfl_xor(mx,1)); mx = fmaxf(mx, __shfl_xor(mx,2));
      mx = fmaxf(mx, __shfl_xor(mx,4)); mx = fmaxf(mx, __shfl_xor(mx,8));
      float sum = 0.f;
#pragma unroll
      for (int st=0; st<9; st++){ v[st] = __expf(v[st]-mx); sum += v[st]; }
      sum += __shfl_xor(sum,1); sum += __shfl_xor(sum,2);
      sum += __shfl_xor(sum,4); sum += __shfl_xor(sum,8);
      const float ivs = 1.0f/sum;
#pragma unroll
      for (int st=0; st<9; st++){
        const int hi2 = (2*st + hi) & 3;
        const int cw  = 2*g + (hi2 & 1) + 8*(2*r + (hi2 >> 1));
        Pfw[(st>>1)*512 + cw*8 + j7] = f2b(v[st]*ivs);
      }
    }
    asm volatile("s_waitcnt lgkmcnt(0)" ::: "memory");
    __builtin_amdgcn_sched_barrier(0);
    bf16x8 a5[5];
#pragma unroll
    for (int ks=0; ks<5; ks++) a5[ks] = *(const bf16x8*)(Pfw + ks*512 + c_r*8);
#pragma unroll
    for (int nt=0; nt<2; nt++){
      f32x4 o; o[0]=0.f; o[1]=0.f; o[2]=0.f; o[3]=0.f;
#pragma unroll
      for (int ks=0; ks<5; ks++){
        const bf16x8 vb = *(const bf16x8*)(Vt + (nt*16 + c15)*SPV + ks*32 + kg);
        mfma16(o, a5[ks], vb);
      }
#pragma unroll
      for (int r=0;r<4;r++){
        const int q = qt*16 + g*4 + r;
        if (q < 134) ao[((size_t)(b*134+q))*256 + h*32 + nt*16 + c15] = f2b(o[r]);
      }
    }
  }
}

// ---------------- fused tail: final LN on cls row + head MLP + dot, one block per batch
// out[b] = gelu(LN(z[b,0,:]) @ hw1 + hb1) @ hw2 + hb2   (all fp32)
__global__ __launch_bounds__(256) void head_f_k(
    const float* __restrict__ z,   const float* __restrict__ lnfg, const float* __restrict__ lnfb,
    const float* __restrict__ hw1, const float* __restrict__ hb1,
    const float* __restrict__ hw2, const float* __restrict__ hb2,
    float* __restrict__ out)
{
  __shared__ float cr[256];
  __shared__ float ps[4];
  const int b = blockIdx.x, d = threadIdx.x, w = d >> 6;
  const float zv = z[(size_t)(b*134)*256 + d];
  float s = zv;
#pragma unroll
  for (int m=1;m<64;m<<=1) s += __shfl_xor(s, m, 64);
  if ((d & 63) == 0) ps[w] = s;
  __syncthreads();
  const float mean = (ps[0]+ps[1]+ps[2]+ps[3])*(1.f/256.f);
  const float dv = zv - mean;
  float q = dv*dv;
#pragma unroll
  for (int m=1;m<64;m<<=1) q += __shfl_xor(q, m, 64);
  __syncthreads();
  if ((d & 63) == 0) ps[w] = q;
  __syncthreads();
  const float rstd = rsqrtf((ps[0]+ps[1]+ps[2]+ps[3])*(1.f/256.f) + 1e-5f);
  cr[d] = dv*rstd*lnfg[d] + lnfb[d];
  __syncthreads();
  float acc = hb1[d];
#pragma unroll 8
  for (int i=0;i<256;i++) acc += cr[i]*hw1[i*256 + d];
  float v = gelu_f(acc) * hw2[d];
#pragma unroll
  for (int m=1;m<64;m<<=1) v += __shfl_xor(v, m, 64);
  __syncthreads();
  if ((d & 63) == 0) ps[w] = v;
  __syncthreads();
  if (d == 0) out[b] = ps[0]+ps[1]+ps[2]+ps[3] + hb2[0];
}

extern "C" void kernel_launch(void* const* d_in, const int* in_sizes, int n_in,
                              void* d_out, int out_size, void* d_ws, size_t ws_size,
                              hipStream_t stream)
{
  (void)in_sizes; (void)n_in; (void)out_size; (void)ws_size;
  const float* x2d   =(const float*)d_in[0];
  const float* y3d   =(const float*)d_in[1];
  const float* je    =(const float*)d_in[2];
  const float* inw   =(const float*)d_in[3];
  const float* inb   =(const float*)d_in[4];
  const float* cls   =(const float*)d_in[5];
  const float* noedge=(const float*)d_in[6];
  const float* dscale=(const float*)d_in[7];
  const float* gamma =(const float*)d_in[8];
  const float* v2n   =(const float*)d_in[9];
  const float* n2v   =(const float*)d_in[10];
  const float* vself =(const float*)d_in[11];
  const float* ln1g  =(const float*)d_in[12];
  const float* ln1b  =(const float*)d_in[13];
  const float* wq    =(const float*)d_in[14];
  const float* bq    =(const float*)d_in[15];
  const float* wk    =(const float*)d_in[16];
  const float* bk    =(const float*)d_in[17];
  const float* wv    =(const float*)d_in[18];
  const float* bv    =(const float*)d_in[19];
  const float* wo    =(const float*)d_in[20];
  const float* bo    =(const float*)d_in[21];
  const float* ln2g  =(const float*)d_in[22];
  const float* ln2b  =(const float*)d_in[23];
  const float* w1    =(const float*)d_in[24];
  const float* b1    =(const float*)d_in[25];
  const float* w2    =(const float*)d_in[26];
  const float* b2    =(const float*)d_in[27];
  const float* lnfg  =(const float*)d_in[28];
  const float* lnfb  =(const float*)d_in[29];
  const float* hw1   =(const float*)d_in[30];
  const float* hb1   =(const float*)d_in[31];
  const float* hw2   =(const float*)d_in[32];
  const float* hb2   =(const float*)d_in[33];
  const float* adj   =(const float*)d_in[34];
  const float* dist  =(const float*)d_in[35];

  char* wsp = (char*)d_ws; size_t off = 0;
  auto alloc = [&](size_t bytes)->char*{ char* p = wsp + off; off = (off + bytes + 255) & ~(size_t)255; return p; };
  float* z    = (float*)alloc((size_t)MROWS*256*4);   // fp32 residual stream
  u16*   qkv  = (u16*)  alloc((size_t)MROWS*768*2);   // bf16 q|k|v
  u16*   xn   = (u16*)  alloc((size_t)MROWS*256*2);   // bf16 LN output
  u16*   ao   = (u16*)  alloc((size_t)MROWS*256*2);   // bf16 attention out
  u16*   wpack= (u16*)  alloc((size_t)2359296*2);     // packed weights (6 layers)
  float* bqkv = (float*)alloc((size_t)6*768*4);
  float* biasP= (float*)alloc((size_t)144*144*4);     // padded bias, cols>=134 masked
  u16*   h1   = qkv;   // alias: qkv dead after attention, mlp hidden reuses it

  // merged prologue: weight-pack | deg+bias | embed+LN1 (all mutually independent)
  prologue_k<<<PREP_BLKS + BIAS_BLKS + EMB_BLKS, 256, 0, stream>>>(
      wq,wk,wv,wo,w1,w2,bq,bk,bv,wpack,bqkv,
      adj,dist,gamma,noedge,dscale,v2n,n2v,vself,biasP,
      x2d,y3d,je,inw,inb,cls,ln1g,ln1b,z,xn);

  for (int l=0; l<NLAYER; ++l){
    const u16* pq = wpack + (size_t)l*LSTR_E;
    gemm_k<0><<<dim3(1608),256,0,stream>>>(xn, pq, bqkv + l*768, qkv, nullptr, nullptr, 48);
    attn_k<<<6144,192,0,stream>>>(qkv, biasP, ao);
    // O-proj fused: z += ao*Wo + bo ; xn = LN2_l(z)
    gemmf_k<<<MROWS/16,64,0,stream>>>(ao, pq + QKV_E, bo + l*256, z,
                                      ln2g + l*256, ln2b + l*256, xn, 1);
    // MLP1: h1 = bf16(gelu(xn*W1 + b1))  (128x128 tile: 4x B-frag reuse)
    gemm_k<2><<<dim3(MROWS/128,2),256,0,stream>>>(xn, pq + QKV_E + O_E, b1 + l*256, h1, nullptr, nullptr, 16);
    // MLP2 fused: z += h1*W2 + b2 ; xn = LN1_{l+1}(z) (skip LN on last layer)
    const int ln_nxt = (l < 5) ? (l+1) : 0;
    gemmf_k<<<MROWS/16,64,0,stream>>>(h1, pq + QKV_E + 2*O_E, b2 + l*256, z,
                                      ln1g + ln_nxt*256, ln1b + ln_nxt*256, xn, (l<5)?1:0);
  }

  // fused tail: final LN (cls rows) + head MLP + dot, fp32 end-to-end
  head_f_k<<<256,256,0,stream>>>(z, lnfg, lnfb, hw1, hb1, hw2, hb2, (float*)d_out);
}

// Round 18
// 822.774 us; speedup vs baseline: 1.0442x; 1.0442x over previous
//
#include <hip/hip_runtime.h>
#include <stdint.h>

typedef unsigned short u16;
typedef unsigned int   u32;
typedef short bf16x8 __attribute__((ext_vector_type(8)));   // 8 bf16 = 4 VGPR
typedef float f32x4  __attribute__((ext_vector_type(4)));

#define NLAYER 6
#define T_TOK  134
#define MROWS  34304            // 256*134
#define QKV_E  196608           // packed qkv elems per layer (8*48*64*8)
#define O_E    65536            // packed 256x256 matrix elems
#define LSTR_E 393216           // per-layer packed stride (qkv+o+w1+w2)
#define SPV 168                 // V^T LDS row stride (u16): 16B-aligned, bank-floor reads
#define PREP_BLKS  1155
#define BIAS_BLKS  81
#define EMB_BLKS   2144         // MROWS/16

__device__ __forceinline__ float b2f(u16 u){ u32 x=((u32)u)<<16; return __builtin_bit_cast(float,x); }
__device__ __forceinline__ u16 f2b(float f){ u32 x=__builtin_bit_cast(u32,f); return (u16)((x + 0x7fffu + ((x>>16)&1u))>>16); }
__device__ __forceinline__ void mfma16(f32x4& c, bf16x8 a, bf16x8 b){
  asm("v_mfma_f32_16x16x32_bf16 %0, %1, %2, %0" : "+v"(c) : "v"(a), "v"(b));
}
__device__ __forceinline__ float gelu_f(float x){ return 0.5f*x*(1.0f+erff(x*0.70710678118654752f)); }
// async global->LDS, 16B/lane; LDS dest wave-uniform base + lane*16 (HW scatter)
__device__ __forceinline__ void gload16(const u16* g, u16* l){
  __builtin_amdgcn_global_load_lds((const __attribute__((address_space(1))) u32*)g,
                                   (__attribute__((address_space(3))) u32*)l, 16, 0, 0);
}

// ---------------- merged prologue: [0,1155) weight-pack | [1155,1236) deg+bias | [1236,3380) embed+LN1
__global__ __launch_bounds__(256) void prologue_k(
    const float* __restrict__ wq, const float* __restrict__ wk, const float* __restrict__ wv,
    const float* __restrict__ wo, const float* __restrict__ w1, const float* __restrict__ w2,
    const float* __restrict__ bq, const float* __restrict__ bk, const float* __restrict__ bv,
    u16* __restrict__ wpack, float* __restrict__ bqkv,
    const float* __restrict__ adj, const float* __restrict__ dist,
    const float* __restrict__ gamma, const float* __restrict__ noedge,
    const float* __restrict__ dscale, const float* __restrict__ v2n,
    const float* __restrict__ n2v, const float* __restrict__ vself,
    float* __restrict__ biasP,
    const float* __restrict__ x2d, const float* __restrict__ y3d,
    const float* __restrict__ je,  const float* __restrict__ inw,
    const float* __restrict__ inb, const float* __restrict__ cls,
    const float* __restrict__ lg,  const float* __restrict__ lb,
    float* __restrict__ z, u16* __restrict__ xn)
{
  const int bx = blockIdx.x;
  const int tid = threadIdx.x;
  if (bx < PREP_BLKS){
    // ---- weight packing (body verbatim from prep_k)
    const int cid = bx*256 + tid;
    if (cid < 294912) {
      const float* msrc = nullptr; int NT, c, layer = 0, isqkv = 0;
      {
        layer = cid / 49152; int r = cid - layer*49152;
        if      (r < 24576){ NT = 48; c = r;          isqkv = 1; }
        else if (r < 32768){ NT = 16; c = r - 24576;  msrc = wo + layer*65536; }
        else if (r < 40960){ NT = 16; c = r - 32768;  msrc = w1 + layer*65536; }
        else               { NT = 16; c = r - 40960;  msrc = w2 + layer*65536; }
      }
      const int lane = c & 63, ctkk = c >> 6;
      const int ct = ctkk % NT, kk = ctkk / NT;
      const int k = kk*32 + (lane>>4)*8;
      const int n = ct*16 + (lane&15);
      u16 ov[8];
      if (isqkv){
        const int sub = n >> 8, nn = n & 255;
        const float* s3 = (sub==0 ? wq : (sub==1 ? wk : wv)) + layer*65536;
#pragma unroll
        for(int j=0;j<8;j++) ov[j] = f2b(s3[(size_t)(k+j)*256 + nn]);
      } else {
#pragma unroll
        for(int j=0;j<8;j++) ov[j] = f2b(msrc[(size_t)(k+j)*256 + n]);
      }
      *(uint4*)(wpack + (size_t)cid*8) = *(uint4*)ov;
    } else {
      const int id = cid - 294912;
      if (id >= 0 && id < 576){
#pragma unroll
        for(int j=0;j<8;j++){
          const int p = id*8 + j; const int layer = p/768; const int w = p - layer*768;
          bqkv[p] = (w<256) ? bq[layer*256+w] : (w<512) ? bk[layer*256+w-256] : bv[layer*256+w-512];
        }
      }
    }
  } else if (bx < PREP_BLKS + BIAS_BLKS){
    // ---- deg (computed redundantly per block; identical serial j-loop -> bit-identical) + bias
    __shared__ float deg[134];   // [133] = 1/(max+eps)
    if (tid < 133){
      float s = 0.f;
      for (int j=0;j<133;j++) s += adj[tid*133+j];
      deg[tid] = s;
    }
    __syncthreads();
    if (tid == 0){ float m=0.f; for (int i=0;i<133;i++) m = fmaxf(m, deg[i]); deg[133] = 1.0f/(m + 1e-6f); }
    __syncthreads();
    const int idx = (bx - PREP_BLKS)*256 + tid;
    if (idx < 144*144){
      const int t = idx/144, s = idx - t*144;
      float v;
      if (s >= 134)          v = -1e30f;      // softmax mask for padded cols
      else if (t >= 134)     v = 0.f;         // garbage rows, never stored
      else if (t==0 && s==0) v = vself[0];
      else if (t==0)         v = v2n[0];
      else if (s==0)         v = n2v[0];
      else {
        const int i = t-1, j = s-1;
        float e = -gamma[0]*dist[i*133+j];
        if (!(adj[i*133+j] > 0.f)) e += noedge[0];
        e += dscale[0]*(deg[i]+deg[j])*deg[133];
        v = e;
      }
      biasP[idx] = v;
    }
  } else {
    // ---- embedding + fused LN1(layer0): 16 rows/block, wave = 4 rows (body verbatim)
    __shared__ float f[16][37];
    const int g = tid>>6, lane = tid & 63;
    const int base = (bx - PREP_BLKS - BIAS_BLKS)*16;
    for (int idx = tid; idx < 592; idx += 256){
      const int i = idx/37, j = idx - 37*i;
      const int r = base + i, b = r/134, t = r - b*134;
      if (t > 0){
        const int n = t - 1;
        float v;
        if (j < 2)      v = x2d[(size_t)(b*133+n)*2 + j];
        else if (j < 5) v = y3d[(size_t)(b*133+n)*3 + (j-2)];
        else            v = je[(size_t)n*32 + (j-5)];
        f[i][j] = v;
      }
    }
    __syncthreads();
    const int d4 = lane*4;
    const int i0 = 4*g;
    const float4 ib = *(const float4*)(inb + d4);
    float4 o0 = ib, o1 = ib, o2 = ib, o3 = ib;
#pragma unroll
    for (int i=0;i<37;i++){
      const float4 w = *(const float4*)(inw + i*256 + d4);
      const float f0 = f[i0+0][i], f1 = f[i0+1][i], f2 = f[i0+2][i], f3 = f[i0+3][i];
      o0.x += f0*w.x; o0.y += f0*w.y; o0.z += f0*w.z; o0.w += f0*w.w;
      o1.x += f1*w.x; o1.y += f1*w.y; o1.z += f1*w.z; o1.w += f1*w.w;
      o2.x += f2*w.x; o2.y += f2*w.y; o2.z += f2*w.z; o2.w += f2*w.w;
      o3.x += f3*w.x; o3.y += f3*w.y; o3.z += f3*w.z; o3.w += f3*w.w;
    }
    const float4 cv = *(const float4*)(cls + d4);
    const float4 gv = *(const float4*)(lg + d4), bv = *(const float4*)(lb + d4);
#pragma unroll
    for (int p=0;p<4;p++){
      const int r = base + i0 + p;
      const int t = r % 134;
      float4 o = (p==0) ? o0 : (p==1) ? o1 : (p==2) ? o2 : o3;
      if (t == 0) o = cv;
      *(float4*)(z + (size_t)r*256 + d4) = o;
      float s = o.x+o.y+o.z+o.w;
#pragma unroll
      for (int m=1;m<64;m<<=1) s += __shfl_xor(s, m, 64);
      const float mean = s*(1.f/256.f);
      const float dx=o.x-mean, dy=o.y-mean, dz=o.z-mean, dw=o.w-mean;
      float q = dx*dx+dy*dy+dz*dz+dw*dw;
#pragma unroll
      for (int m=1;m<64;m<<=1) q += __shfl_xor(q, m, 64);
      const float rstd = rsqrtf(q*(1.f/256.f) + 1e-5f);
      u32 p0 = (u32)f2b(dx*rstd*gv.x+bv.x) | ((u32)f2b(dy*rstd*gv.y+bv.y)<<16);
      u32 p1 = (u32)f2b(dz*rstd*gv.z+bv.z) | ((u32)f2b(dw*rstd*gv.w+bv.w)<<16);
      uint2 ov; ov.x = p0; ov.y = p1;
      *(uint2*)(xn + (size_t)r*256 + d4) = ov;
    }
  }
}

// ---------------- bf16 MFMA GEMM with global_load_lds staging (m97 pattern)
// EPI==0 (QKV) uses an XCD-chunked 1-D swizzled launch (grid 1608 = 8*201).
template<int EPI>
__global__ __launch_bounds__(256) void gemm_k(
    const u16* __restrict__ A, const u16* __restrict__ PB, const float* __restrict__ bias,
    u16* __restrict__ Obf, float* __restrict__ Of, float* __restrict__ Z, int NT)
{
  const int N = NT*16;
  __shared__ __align__(16) u16 lsA[4096];
  __shared__ __align__(16) u16 lsB[4096];
  const int tid = threadIdx.x, lane = tid & 63, wid = tid >> 6;
  int m0, n0;
  if constexpr (EPI==0){
    const int g = blockIdx.x;
    const int wg = (g & 7)*201 + (g >> 3);
    m0 = (wg/6)*128; n0 = (wg%6)*128;
  } else {
    m0 = blockIdx.x*128; n0 = blockIdx.y*128;
  }
  const int wr = wid >> 1, wc = wid & 1;
  f32x4 acc[4][4];
#pragma unroll
  for (int i=0;i<4;i++)
#pragma unroll
    for (int j=0;j<4;j++){ acc[i][j][0]=0.f; acc[i][j][1]=0.f; acc[i][j][2]=0.f; acc[i][j][3]=0.f; }

  const u16* gA0 = A + (size_t)(m0 + wid*32 + (lane&15))*256 + (lane>>4)*8;
  const u16* gA1 = gA0 + 16*256;
  u16* lA0 = lsA + wid*1024;
  u16* lA1 = lA0 + 512;
  const size_t bstr = (size_t)NT*512;
  const u16* gB0 = PB + ((size_t)((n0>>4) + wid)*64 + lane)*8;
  const u16* gB1 = gB0 + 4*512;
  u16* lB0 = lsB + wid*512;
  u16* lB1 = lB0 + 4*512;

  for (int kk=0; kk<8; ++kk){
    gload16(gA0 + kk*32, lA0);
    gload16(gA1 + kk*32, lA1);
    gload16(gB0 + (size_t)kk*bstr, lB0);
    gload16(gB1 + (size_t)kk*bstr, lB1);
    __syncthreads();
    bf16x8 af[4], bfr[4];
#pragma unroll
    for (int mi=0;mi<4;mi++) af[mi]  = *(const bf16x8*)(lsA + ((wr*4+mi)*64 + lane)*8);
#pragma unroll
    for (int ni=0;ni<4;ni++) bfr[ni] = *(const bf16x8*)(lsB + ((wc*4+ni)*64 + lane)*8);
#pragma unroll
    for (int mi=0;mi<4;mi++)
#pragma unroll
      for (int ni=0;ni<4;ni++)
        mfma16(acc[mi][ni], af[mi], bfr[ni]);
    __syncthreads();
  }
  const int r0 = (lane>>4)*4, c15 = lane & 15;
#pragma unroll
  for (int mi=0;mi<4;mi++){
#pragma unroll
    for (int ni=0;ni<4;ni++){
      const int col = n0 + wc*64 + ni*16 + c15;
      const float bv = bias[col];
#pragma unroll
      for (int r=0;r<4;r++){
        const int row = m0 + wr*64 + mi*16 + r0 + r;
        float v = acc[mi][ni][r] + bv;
        if constexpr (EPI==0){ Obf[(size_t)row*N + col] = f2b(v); }
        else if constexpr (EPI==1){ Z[(size_t)row*256 + col] += v; }
        else if constexpr (EPI==2){ Obf[(size_t)row*N + col] = f2b(gelu_f(v)); }
        else { Of[(size_t)row*N + col] = gelu_f(v); }
      }
    }
  }
}

// ---------------- fused full-row GEMM, 32 rows x 256 cols, 2 waves (round-16 green).
// mode 0: Z += A*W + b ; mode 1: Z += A*W + b ; xn = LN(Z)
__global__ __launch_bounds__(128) void gemmf_k(
    const u16* __restrict__ A, const u16* __restrict__ PB, const float* __restrict__ bias,
    float* __restrict__ Z, const float* __restrict__ lg, const float* __restrict__ lb,
    u16* __restrict__ xn, int mode)
{
  __shared__ __align__(16) u16 lsA[1024];   // 2 chunks [64][8]
  __shared__ __align__(16) u16 lsB[8192];   // 16 chunks [64][8]
  const int tid = threadIdx.x, lane = tid & 63, w = tid >> 6;
  const int m0 = blockIdx.x*32;
  f32x4 acc[16];
#pragma unroll
  for (int ni=0;ni<16;ni++){ acc[ni][0]=0.f; acc[ni][1]=0.f; acc[ni][2]=0.f; acc[ni][3]=0.f; }

  const u16* gA = A + (size_t)(m0 + w*16 + (lane&15))*256 + (lane>>4)*8;
  u16* lA = lsA + w*512;
  const u16* gB0 = PB + (size_t)(w*8)*512 + (size_t)lane*8;

  for (int kk=0; kk<8; ++kk){
    gload16(gA + kk*32, lA);
#pragma unroll
    for (int i=0;i<8;i++) gload16(gB0 + (size_t)kk*8192 + i*512, lsB + (w*8+i)*512);
    __syncthreads();
    const bf16x8 af = *(const bf16x8*)(lsA + w*512 + lane*8);
#pragma unroll
    for (int ni=0;ni<16;ni++){
      const bf16x8 bfr = *(const bf16x8*)(lsB + ni*512 + lane*8);
      mfma16(acc[ni], af, bfr);
    }
    __syncthreads();
  }

  const int g4 = lane>>4, c15 = lane & 15;
  float bvs[16];
#pragma unroll
  for (int ni=0;ni<16;ni++) bvs[ni] = bias[ni*16+c15];
#pragma unroll
  for (int r=0;r<4;r++){
    const int row = m0 + w*16 + g4*4 + r;
    float* zr = Z + (size_t)row*256;
    float zv[16]; float s = 0.f;
#pragma unroll
    for (int ni=0;ni<16;ni++){ zv[ni] = acc[ni][r] + bvs[ni] + zr[ni*16+c15]; s += zv[ni]; }
#pragma unroll
    for (int ni=0;ni<16;ni++) zr[ni*16+c15] = zv[ni];
    if (mode == 1){
      s += __shfl_xor(s,1,16); s += __shfl_xor(s,2,16);
      s += __shfl_xor(s,4,16); s += __shfl_xor(s,8,16);
      const float mean = s*(1.f/256.f);
      float q = 0.f;
#pragma unroll
      for (int ni=0;ni<16;ni++){ const float d = zv[ni]-mean; q += d*d; }
      q += __shfl_xor(q,1,16); q += __shfl_xor(q,2,16);
      q += __shfl_xor(q,4,16); q += __shfl_xor(q,8,16);
      const float rstd = rsqrtf(q*(1.f/256.f) + 1e-5f);
      u16* xr = xn + (size_t)row*256;
#pragma unroll
      for (int ni=0;ni<16;ni++){
        const int col = ni*16 + c15;
        xr[col] = f2b((zv[ni]-mean)*rstd*lg[col] + lb[col]);
      }
    }
  }
}

// ---------------- MFMA flash attention (round-4 math, thirds-split):
// 3 blocks per (b,h); each block = 3 waves x ONE q-tile (qt = t3*3 + w).
// Fence-1 removed (no prior Pf reads with single q-tile per wave).
// This body is the verified round-11/13 version — do not micro-edit.
__global__ __launch_bounds__(192, 6) void attn_k(
    const u16* __restrict__ qkv, const float* __restrict__ biasP, u16* __restrict__ ao)
{
  const int g0 = blockIdx.x;
  const int blk = (g0 & 7)*768 + (g0 >> 3);   // bijective XCD chunking
  const int bh = blk/3, t3 = blk - 3*bh;
  const int b = bh >> 3, h = bh & 7;
  __shared__ __align__(16) u16 Pf[3*2560];     // per-wave 5 ks * 64 lanes * 8 u16
  __shared__ __align__(16) u16 Vt[32*SPV];     // V^T [d][s], s zero-padded to 160
  const int tid = threadIdx.x, lane = tid & 63, w = tid >> 6;
  const int g = lane >> 4, c15 = lane & 15;
  const size_t base = (size_t)b*134*768 + h*32;

  if (tid < 134){
    const uint4* vr = (const uint4*)(qkv + base + (size_t)tid*768 + 512);
    uint4 w0=vr[0], w1=vr[1], w2=vr[2], w3=vr[3];
    u32 wa[8] = {w0.x,w0.y,w0.z,w0.w,w1.x,w1.y,w1.z,w1.w};
    u32 wb[8] = {w2.x,w2.y,w2.z,w2.w,w3.x,w3.y,w3.z,w3.w};
#pragma unroll
    for (int k=0;k<8;k++){
      Vt[(2*k  )*SPV + tid] = (u16)(wa[k] & 0xffffu);
      Vt[(2*k+1)*SPV + tid] = (u16)(wa[k] >> 16);
      Vt[(16+2*k  )*SPV + tid] = (u16)(wb[k] & 0xffffu);
      Vt[(16+2*k+1)*SPV + tid] = (u16)(wb[k] >> 16);
    }
  } else if (tid < 160){
#pragma unroll
    for (int d=0; d<32; d++) Vt[d*SPV + tid] = 0;
  }
  u16* Pfw = Pf + w*2560;
  const int c_r = 2*(c15>>2) + (g&1) + 8*(2*(c15&3) + (g>>1));
  if (lane >= 32){ uint4 zz; zz.x=0u; zz.y=0u; zz.z=0u; zz.w=0u;
                   *(uint4*)(Pfw + 4*512 + c_r*8) = zz; }
  __syncthreads();

  bf16x8 kf[9];
  const int kg = g*8;
#pragma unroll
  for (int st=0; st<9; st++){
    int sr = st*16 + c15; if (sr > 133) sr = 133;
    kf[st] = *(const bf16x8*)(qkv + base + (size_t)sr*768 + 256 + kg);
  }
  const float isq = 0.17677669529663687f;

  {
    const int qt = t3*3 + w;
    int qr = qt*16 + c15; if (qr > 133) qr = 133;
    const bf16x8 qf = *(const bf16x8*)(qkv + base + (size_t)qr*768 + kg);
    f32x4 s_[9];
#pragma unroll
    for (int st=0; st<9; st++){
      s_[st][0]=0.f; s_[st][1]=0.f; s_[st][2]=0.f; s_[st][3]=0.f;
      mfma16(s_[st], qf, kf[st]);
    }
    const int hi = c15 >> 3, j7 = c15 & 7;
#pragma unroll
    for (int r=0;r<4;r++){
      const float* br = biasP + (size_t)(qt*16 + g*4 + r)*144 + c15;
      float v[9];
#pragma unroll
      for (int st=0; st<9; st++) v[st] = s_[st][r]*isq + br[st*16];
      float mx = v[0];
#pragma unroll
      for (int st=1; st<9; st++) mx = fmaxf(mx, v[st]);
      mx = fmaxf(mx, __shfl_xor(mx,1)); mx = fmaxf(mx, __shfl_xor(mx,2));
      mx = fmaxf(mx, __shfl_xor(mx,4)); mx = fmaxf(mx, __shfl_xor(mx,8));
      float sum = 0.f;
#pragma unroll
      for (int st=0; st<9; st++){ v[st] = __expf(v[st]-mx); sum += v[st]; }
      sum += __shfl_xor(sum,1); sum += __shfl_xor(sum,2);
      sum += __shfl_xor(sum,4); sum += __shfl_xor(sum,8);
      const float ivs = 1.0f/sum;
#pragma unroll
      for (int st=0; st<9; st++){
        const int hi2 = (2*st + hi) & 3;
        const int cw  = 2*g + (hi2 & 1) + 8*(2*r + (hi2 >> 1));
        Pfw[(st>>1)*512 + cw*8 + j7] = f2b(v[st]*ivs);
      }
    }
    asm volatile("s_waitcnt lgkmcnt(0)" ::: "memory");
    __builtin_amdgcn_sched_barrier(0);
    bf16x8 a5[5];
#pragma unroll
    for (int ks=0; ks<5; ks++) a5[ks] = *(const bf16x8*)(Pfw + ks*512 + c_r*8);
#pragma unroll
    for (int nt=0; nt<2; nt++){
      f32x4 o; o[0]=0.f; o[1]=0.f; o[2]=0.f; o[3]=0.f;
#pragma unroll
      for (int ks=0; ks<5; ks++){
        const bf16x8 vb = *(const bf16x8*)(Vt + (nt*16 + c15)*SPV + ks*32 + kg);
        mfma16(o, a5[ks], vb);
      }
#pragma unroll
      for (int r=0;r<4;r++){
        const int q = qt*16 + g*4 + r;
        if (q < 134) ao[((size_t)(b*134+q))*256 + h*32 + nt*16 + c15] = f2b(o[r]);
      }
    }
  }
}

// ---------------- fused tail: final LN on cls row + head MLP + dot, one block per batch
// out[b] = gelu(LN(z[b,0,:]) @ hw1 + hb1) @ hw2 + hb2   (all fp32)
__global__ __launch_bounds__(256) void head_f_k(
    const float* __restrict__ z,   const float* __restrict__ lnfg, const float* __restrict__ lnfb,
    const float* __restrict__ hw1, const float* __restrict__ hb1,
    const float* __restrict__ hw2, const float* __restrict__ hb2,
    float* __restrict__ out)
{
  __shared__ float cr[256];
  __shared__ float ps[4];
  const int b = blockIdx.x, d = threadIdx.x, w = d >> 6;
  const float zv = z[(size_t)(b*134)*256 + d];
  float s = zv;
#pragma unroll
  for (int m=1;m<64;m<<=1) s += __shfl_xor(s, m, 64);
  if ((d & 63) == 0) ps[w] = s;
  __syncthreads();
  const float mean = (ps[0]+ps[1]+ps[2]+ps[3])*(1.f/256.f);
  const float dv = zv - mean;
  float q = dv*dv;
#pragma unroll
  for (int m=1;m<64;m<<=1) q += __shfl_xor(q, m, 64);
  __syncthreads();
  if ((d & 63) == 0) ps[w] = q;
  __syncthreads();
  const float rstd = rsqrtf((ps[0]+ps[1]+ps[2]+ps[3])*(1.f/256.f) + 1e-5f);
  cr[d] = dv*rstd*lnfg[d] + lnfb[d];
  __syncthreads();
  float acc = hb1[d];
#pragma unroll 8
  for (int i=0;i<256;i++) acc += cr[i]*hw1[i*256 + d];
  float v = gelu_f(acc) * hw2[d];
#pragma unroll
  for (int m=1;m<64;m<<=1) v += __shfl_xor(v, m, 64);
  __syncthreads();
  if ((d & 63) == 0) ps[w] = v;
  __syncthreads();
  if (d == 0) out[b] = ps[0]+ps[1]+ps[2]+ps[3] + hb2[0];
}

extern "C" void kernel_launch(void* const* d_in, const int* in_sizes, int n_in,
                              void* d_out, int out_size, void* d_ws, size_t ws_size,
                              hipStream_t stream)
{
  (void)in_sizes; (void)n_in; (void)out_size; (void)ws_size;
  const float* x2d   =(const float*)d_in[0];
  const float* y3d   =(const float*)d_in[1];
  const float* je    =(const float*)d_in[2];
  const float* inw   =(const float*)d_in[3];
  const float* inb   =(const float*)d_in[4];
  const float* cls   =(const float*)d_in[5];
  const float* noedge=(const float*)d_in[6];
  const float* dscale=(const float*)d_in[7];
  const float* gamma =(const float*)d_in[8];
  const float* v2n   =(const float*)d_in[9];
  const float* n2v   =(const float*)d_in[10];
  const float* vself =(const float*)d_in[11];
  const float* ln1g  =(const float*)d_in[12];
  const float* ln1b  =(const float*)d_in[13];
  const float* wq    =(const float*)d_in[14];
  const float* bq    =(const float*)d_in[15];
  const float* wk    =(const float*)d_in[16];
  const float* bk    =(const float*)d_in[17];
  const float* wv    =(const float*)d_in[18];
  const float* bv    =(const float*)d_in[19];
  const float* wo    =(const float*)d_in[20];
  const float* bo    =(const float*)d_in[21];
  const float* ln2g  =(const float*)d_in[22];
  const float* ln2b  =(const float*)d_in[23];
  const float* w1    =(const float*)d_in[24];
  const float* b1    =(const float*)d_in[25];
  const float* w2    =(const float*)d_in[26];
  const float* b2    =(const float*)d_in[27];
  const float* lnfg  =(const float*)d_in[28];
  const float* lnfb  =(const float*)d_in[29];
  const float* hw1   =(const float*)d_in[30];
  const float* hb1   =(const float*)d_in[31];
  const float* hw2   =(const float*)d_in[32];
  const float* hb2   =(const float*)d_in[33];
  const float* adj   =(const float*)d_in[34];
  const float* dist  =(const float*)d_in[35];

  char* wsp = (char*)d_ws; size_t off = 0;
  auto alloc = [&](size_t bytes)->char*{ char* p = wsp + off; off = (off + bytes + 255) & ~(size_t)255; return p; };
  float* z    = (float*)alloc((size_t)MROWS*256*4);   // fp32 residual stream
  u16*   qkv  = (u16*)  alloc((size_t)MROWS*768*2);   // bf16 q|k|v
  u16*   xn   = (u16*)  alloc((size_t)MROWS*256*2);   // bf16 LN output
  u16*   ao   = (u16*)  alloc((size_t)MROWS*256*2);   // bf16 attention out
  u16*   wpack= (u16*)  alloc((size_t)2359296*2);     // packed weights (6 layers)
  float* bqkv = (float*)alloc((size_t)6*768*4);
  float* biasP= (float*)alloc((size_t)144*144*4);     // padded bias, cols>=134 masked
  u16*   h1   = qkv;   // alias: qkv dead after attention, mlp hidden reuses it

  // merged prologue: weight-pack | deg+bias | embed+LN1 (all mutually independent)
  prologue_k<<<PREP_BLKS + BIAS_BLKS + EMB_BLKS, 256, 0, stream>>>(
      wq,wk,wv,wo,w1,w2,bq,bk,bv,wpack,bqkv,
      adj,dist,gamma,noedge,dscale,v2n,n2v,vself,biasP,
      x2d,y3d,je,inw,inb,cls,ln1g,ln1b,z,xn);

  for (int l=0; l<NLAYER; ++l){
    const u16* pq = wpack + (size_t)l*LSTR_E;
    gemm_k<0><<<dim3(1608),256,0,stream>>>(xn, pq, bqkv + l*768, qkv, nullptr, nullptr, 48);
    attn_k<<<6144,192,0,stream>>>(qkv, biasP, ao);
    // O-proj fused: z += ao*Wo + bo ; xn = LN2_l(z)
    gemmf_k<<<MROWS/32,128,0,stream>>>(ao, pq + QKV_E, bo + l*256, z,
                                       ln2g + l*256, ln2b + l*256, xn, 1);
    // MLP1: h1 = bf16(gelu(xn*W1 + b1))  (128x128 tile: 4x B-frag reuse)
    gemm_k<2><<<dim3(MROWS/128,2),256,0,stream>>>(xn, pq + QKV_E + O_E, b1 + l*256, h1, nullptr, nullptr, 16);
    // MLP2 fused: z += h1*W2 + b2 ; xn = LN1_{l+1}(z) (skip LN on last layer)
    const int ln_nxt = (l < 5) ? (l+1) : 0;
    gemmf_k<<<MROWS/32,128,0,stream>>>(h1, pq + QKV_E + 2*O_E, b2 + l*256, z,
                                       ln1g + ln_nxt*256, ln1b + ln_nxt*256, xn, (l<5)?1:0);
  }

  // fused tail: final LN (cls rows) + head MLP + dot, fp32 end-to-end
  head_f_k<<<256,256,0,stream>>>(z, lnfg, lnfb, hw1, hb1, hw2, hb2, (float*)d_out);
}